// Round 11
// baseline (105.732 us; speedup 1.0000x reference)
//
#include <hip/hip_runtime.h>

// QPLayer: per-batch dual QP via 400 fixed PGD iterations — EXACT reference
// trajectory (R6: some problems are NOT converged at 400 iters -> output is
// trajectory-dependent; alpha stays 1/(2||A^T A||_F + 1e-6), iters stay 400).
// Math: q = b (x cancels), alpha = 1/(2||A^T A||_F + 1e-6),
//   lam <- relu(lam - alpha*b - 2*alpha*A(A^T lam)),  out = -A^T lam.
// Pre-scale A' = sqrt(2*alpha)*A:  lam <- relu(lam - alpha*b - A'(A'^T lam)),
//   out = -(1/sc) A'^T lam, sc = sqrt(2*alpha).
//
// R11 experiment: ALL-SCALAR fmac-shaped code at the slot-minimal 2-lane
// geometry, fully merged loop. Evidence so far: R8 (2 waves), R9 (2x ILP),
// R10 (fewer slots) all land 102-109 rocprof -> flat; model: scalar
// v_fma_f32 is the full-rate path (157 TF spec = scalar rate), v_pk_fma_f32
// is NOT double-throughput on gfx950, so packing only bought code density.
// This variant: scalar fmac accumulation (VOP2-encodable), explicit
// xor-negation of the broadcast u (keeps fmac form), update+next-iter-u
// merged into ONE k-loop (same arithmetic order; epilogue A'^T lam is free).
// 32768 x 2 lanes = 65536 threads = 1024 waves = 1 wave/SIMD.

#define QP_ITERS 400

template <int CTRL>
__device__ __forceinline__ float dpp_add(float v) {
    // fused v_add_f32_dpp (old = 0, bound_ctrl = 1)
    return v + __int_as_float(
        __builtin_amdgcn_update_dpp(0, __float_as_int(v), CTRL, 0xF, 0xF, true));
}

__device__ __forceinline__ float pair_sum(float v) {
    return dpp_add<0xB1>(v);   // quad_perm(1,0,3,2): xor 1 — sums lane pair
}

__device__ __forceinline__ float fneg_bits(float v) {
    return __int_as_float(__float_as_int(v) ^ 0x80000000);
}

__global__ void __launch_bounds__(256)
__attribute__((amdgpu_waves_per_eu(1, 1)))
qp_pgd_kernel(
        const float* __restrict__ A,   // [nprob, 32, 4]
        const float* __restrict__ b,   // [nprob, 32]
        float* __restrict__ out,       // [nprob, 4]
        int nprob) {
    int t = blockIdx.x * blockDim.x + threadIdx.x;
    int p = t >> 1;          // problem index
    int j = t & 1;           // lane within pair
    if (p >= nprob) return;

    // Lane j owns rows 16j .. 16j+15.
    const float4* Ar = reinterpret_cast<const float4*>(A + (size_t)p * 128 + (size_t)j * 64);
    const float4* br = reinterpret_cast<const float4*>(b + (size_t)p * 32 + (size_t)j * 16);

    float ax[16], ay[16], az[16], aw[16];
#pragma unroll
    for (int k = 0; k < 16; ++k) {
        float4 r = Ar[k];
        ax[k] = r.x; ay[k] = r.y; az[k] = r.z; aw[k] = r.w;
    }
    float bb[16];
#pragma unroll
    for (int k = 0; k < 4; ++k) {
        float4 bv = br[k];
        bb[4 * k + 0] = bv.x; bb[4 * k + 1] = bv.y;
        bb[4 * k + 2] = bv.z; bb[4 * k + 3] = bv.w;
    }

    // ---- alpha = 1 / (2*||A^T A||_F + 1e-6)  (Frobenius — reference exact) ----
    float s00 = 0.f, s01 = 0.f, s02 = 0.f, s03 = 0.f;
    float s11 = 0.f, s12 = 0.f, s13 = 0.f;
    float s22 = 0.f, s23 = 0.f, s33 = 0.f;
#pragma unroll
    for (int k = 0; k < 16; ++k) {
        s00 = fmaf(ax[k], ax[k], s00);
        s01 = fmaf(ax[k], ay[k], s01);
        s02 = fmaf(ax[k], az[k], s02);
        s03 = fmaf(ax[k], aw[k], s03);
        s11 = fmaf(ay[k], ay[k], s11);
        s12 = fmaf(ay[k], az[k], s12);
        s13 = fmaf(ay[k], aw[k], s13);
        s22 = fmaf(az[k], az[k], s22);
        s23 = fmaf(az[k], aw[k], s23);
        s33 = fmaf(aw[k], aw[k], s33);
    }
    s00 = pair_sum(s00); s01 = pair_sum(s01); s02 = pair_sum(s02); s03 = pair_sum(s03);
    s11 = pair_sum(s11); s12 = pair_sum(s12); s13 = pair_sum(s13);
    s22 = pair_sum(s22); s23 = pair_sum(s23); s33 = pair_sum(s33);
    float ssq = s00 * s00 + s11 * s11 + s22 * s22 + s33 * s33
              + 2.f * (s01 * s01 + s02 * s02 + s03 * s03
                     + s12 * s12 + s13 * s13 + s23 * s23);
    float L = 2.f * sqrtf(ssq) + 1e-6f;
    float alpha = 1.f / L;
    float sc = sqrtf(2.f * alpha);     // A' = sc * A
    float inv_sc = 1.f / sc;

    float mc[16], lam[16];
#pragma unroll
    for (int k = 0; k < 16; ++k) {
        ax[k] *= sc; ay[k] *= sc; az[k] *= sc; aw[k] *= sc;
        mc[k] = -alpha * bb[k];
        lam[k] = 0.f;
    }

    // ---- merged PGD loop: per iter {reduce u, update lam, accumulate next u} ----
    // Prologue u = A'^T lam0 = 0.
    float u0 = 0.f, u1 = 0.f, u2 = 0.f, u3 = 0.f;

    for (int it = 0; it < QP_ITERS; ++it) {
        // cross-lane completion of u (per-lane partials -> full sums)
        float U0 = pair_sum(u0), U1 = pair_sum(u1);
        float U2 = pair_sum(u2), U3 = pair_sum(u3);
        float n0 = fneg_bits(U0), n1 = fneg_bits(U1);
        float n2 = fneg_bits(U2), n3 = fneg_bits(U3);
        u0 = 0.f; u1 = 0.f; u2 = 0.f; u3 = 0.f;
#pragma unroll
        for (int k = 0; k < 16; ++k) {
            // lam[k] = relu(lam[k] + mc[k] - A'[k]·U)
            float tt = lam[k] + mc[k];
            tt = fmaf(ax[k], n0, tt);
            tt = fmaf(ay[k], n1, tt);
            tt = fmaf(az[k], n2, tt);
            tt = fmaf(aw[k], n3, tt);
            float l = fmaxf(tt, 0.f);
            lam[k] = l;
            // accumulate next iteration's u partials (same order as split loop)
            u0 = fmaf(ax[k], l, u0);
            u1 = fmaf(ay[k], l, u1);
            u2 = fmaf(az[k], l, u2);
            u3 = fmaf(aw[k], l, u3);
        }
    }

    // ---- output: u already holds A'^T lam_400 partials ----
    float U0 = pair_sum(u0), U1 = pair_sum(u1);
    float U2 = pair_sum(u2), U3 = pair_sum(u3);
    // lane j writes components 2j, 2j+1 (8B float2 store, lane-consecutive)
    float lo = (j == 0) ? U0 : U2;
    float hi = (j == 0) ? U1 : U3;
    float2 o = make_float2(-lo * inv_sc, -hi * inv_sc);
    *reinterpret_cast<float2*>(out + (size_t)p * 4 + (size_t)j * 2) = o;
}

extern "C" void kernel_launch(void* const* d_in, const int* in_sizes, int n_in,
                              void* d_out, int out_size, void* d_ws, size_t ws_size,
                              hipStream_t stream) {
    const float* A = (const float*)d_in[0];
    // d_in[1] (x) cancels analytically and is unused.
    const float* b = (const float*)d_in[2];
    float* out = (float*)d_out;

    int nprob = in_sizes[2] / 32;          // B = 32768
    int threads = nprob * 2;               // 2 lanes per problem
    dim3 block(256);
    dim3 grid((threads + 255) / 256);
    hipLaunchKernelGGL(qp_pgd_kernel, grid, block, 0, stream, A, b, out, nprob);
}

// Round 12
// 87.528 us; speedup vs baseline: 1.2080x; 1.2080x over previous
//
#include <hip/hip_runtime.h>

// QPLayer: per-batch dual QP via 400 fixed PGD iterations — EXACT reference
// trajectory (R6: some problems are NOT converged at 400 iters -> output is
// trajectory-dependent; alpha stays 1/(2||A^T A||_F)+1e-6 form, iters 400).
// Math: q = b (x cancels), L = 2*||A^T A||_F + 1e-6, alpha = 1/L,
//   lam <- relu(lam - alpha*b - 2*alpha*A(A^T lam)),  out = -A^T lam.
// Pre-scale A' = sqrt(2*alpha)*A:  lam <- relu(lam - alpha*b - A'(A'^T lam)),
//   out = -(1/sc) A'^T lam, sc = sqrt(2*alpha).
//
// FINAL (R12 = R10, session best: 87 us wall / 102 us rocprof):
// 2 lanes/problem — slot-minimal geometry. 32768 x 2 lanes = 65536 threads
// = 1024 waves = 1 wave/SIMD, full SIMD coverage. Packed fp32 via native
// <2 x float> ops (backend emits v_pk_fma_f32/v_pk_add_f32/v_pk_max_f32):
// ~80 pk-slots/iter carrying 512 MAC-FLOPs/problem/iter.
//
// Session model (R1-R11): landscape is flat 102-160 us across wave count
// (R8), per-thread ILP (R9), lane split (R2/R10), scalar vs packed (R7/R11),
// register budget (R4/R5). Pin = practical VALU rate (m07: 103 of 157 TF).
// Total mandated arithmetic ~7.9 GFLOP fp32 -> ~77 us at practical ceiling;
// this kernel's busy time ~68 us => within ~15% of hardware-practical.
// Trajectory cannot be shortened: R3 (early exit) never fired profitably,
// R6 (sharper step / fewer iters) FAILED correctness.

#define QP_ITERS 400

typedef float v2f __attribute__((ext_vector_type(2)));

template <int CTRL>
__device__ __forceinline__ float dpp_add(float v) {
    // fused v_add_f32_dpp (old = 0, bound_ctrl = 1)
    return v + __int_as_float(
        __builtin_amdgcn_update_dpp(0, __float_as_int(v), CTRL, 0xF, 0xF, true));
}

__device__ __forceinline__ float pair_sum(float v) {
    return dpp_add<0xB1>(v);   // quad_perm(1,0,3,2): xor 1 — sums lane pair (2k,2k+1)
}

__global__ void __launch_bounds__(256)
__attribute__((amdgpu_waves_per_eu(1, 1)))
qp_pgd_kernel(
        const float* __restrict__ A,   // [nprob, 32, 4]
        const float* __restrict__ b,   // [nprob, 32]
        float* __restrict__ out,       // [nprob, 4]
        int nprob) {
    int t = blockIdx.x * blockDim.x + threadIdx.x;
    int p = t >> 1;          // problem index
    int j = t & 1;           // lane within pair
    if (p >= nprob) return;

    // Lane j owns rows 16j .. 16j+15 (8 row-pairs).
    const float4* Ar = reinterpret_cast<const float4*>(A + (size_t)p * 128 + (size_t)j * 64);
    const float4* br = reinterpret_cast<const float4*>(b + (size_t)p * 32 + (size_t)j * 16);

    float ax[16], ay[16], az[16], aw[16];
#pragma unroll
    for (int k = 0; k < 16; ++k) {
        float4 r = Ar[k];
        ax[k] = r.x; ay[k] = r.y; az[k] = r.z; aw[k] = r.w;
    }
    float bb[16];
#pragma unroll
    for (int k = 0; k < 4; ++k) {
        float4 bv = br[k];
        bb[4 * k + 0] = bv.x; bb[4 * k + 1] = bv.y;
        bb[4 * k + 2] = bv.z; bb[4 * k + 3] = bv.w;
    }

    // ---- alpha = 1 / (2*||A^T A||_F + 1e-6)  (Frobenius — reference exact) ----
    float s00 = 0.f, s01 = 0.f, s02 = 0.f, s03 = 0.f;
    float s11 = 0.f, s12 = 0.f, s13 = 0.f;
    float s22 = 0.f, s23 = 0.f, s33 = 0.f;
#pragma unroll
    for (int k = 0; k < 16; ++k) {
        s00 = fmaf(ax[k], ax[k], s00);
        s01 = fmaf(ax[k], ay[k], s01);
        s02 = fmaf(ax[k], az[k], s02);
        s03 = fmaf(ax[k], aw[k], s03);
        s11 = fmaf(ay[k], ay[k], s11);
        s12 = fmaf(ay[k], az[k], s12);
        s13 = fmaf(ay[k], aw[k], s13);
        s22 = fmaf(az[k], az[k], s22);
        s23 = fmaf(az[k], aw[k], s23);
        s33 = fmaf(aw[k], aw[k], s33);
    }
    s00 = pair_sum(s00); s01 = pair_sum(s01); s02 = pair_sum(s02); s03 = pair_sum(s03);
    s11 = pair_sum(s11); s12 = pair_sum(s12); s13 = pair_sum(s13);
    s22 = pair_sum(s22); s23 = pair_sum(s23); s33 = pair_sum(s33);
    float ssq = s00 * s00 + s11 * s11 + s22 * s22 + s33 * s33
              + 2.f * (s01 * s01 + s02 * s02 + s03 * s03
                     + s12 * s12 + s13 * s13 + s23 * s23);
    float L = 2.f * sqrtf(ssq) + 1e-6f;
    float alpha = 1.f / L;
    float sc = sqrtf(2.f * alpha);     // A' = sc * A
    float inv_sc = 1.f / sc;

    // ---- pack rows into 8 pairs (2i, 2i+1), pre-scaled; mc = -alpha*b ----
    v2f axp[8], ayp[8], azp[8], awp[8], mcp[8], lamp[8];
#pragma unroll
    for (int i = 0; i < 8; ++i) {
        axp[i] = (v2f){ax[2 * i] * sc, ax[2 * i + 1] * sc};
        ayp[i] = (v2f){ay[2 * i] * sc, ay[2 * i + 1] * sc};
        azp[i] = (v2f){az[2 * i] * sc, az[2 * i + 1] * sc};
        awp[i] = (v2f){aw[2 * i] * sc, aw[2 * i + 1] * sc};
        mcp[i] = (v2f){-alpha * bb[2 * i], -alpha * bb[2 * i + 1]};
        lamp[i] = (v2f){0.f, 0.f};
    }

    // ---- 400 PGD iterations ----
#pragma unroll 2
    for (int it = 0; it < QP_ITERS; ++it) {
        // u' = A'^T lam : 4 packed chains over 8 row-pairs
        v2f a0 = (v2f){0.f, 0.f}, a1 = (v2f){0.f, 0.f};
        v2f a2 = (v2f){0.f, 0.f}, a3 = (v2f){0.f, 0.f};
#pragma unroll
        for (int i = 0; i < 8; ++i) {
            a0 = __builtin_elementwise_fma(axp[i], lamp[i], a0);
            a1 = __builtin_elementwise_fma(ayp[i], lamp[i], a1);
            a2 = __builtin_elementwise_fma(azp[i], lamp[i], a2);
            a3 = __builtin_elementwise_fma(awp[i], lamp[i], a3);
        }
        // fold halves, then single-stage pair reduce (sum + broadcast in one)
        float u0 = pair_sum(a0.x + a0.y);
        float u1 = pair_sum(a1.x + a1.y);
        float u2 = pair_sum(a2.x + a2.y);
        float u3 = pair_sum(a3.x + a3.y);
        v2f U0 = (v2f){-u0, -u0}, U1 = (v2f){-u1, -u1};
        v2f U2 = (v2f){-u2, -u2}, U3 = (v2f){-u3, -u3};
        const v2f z2 = (v2f){0.f, 0.f};
        // lam = relu(lam - alpha*b - A'·u')  per row-pair
#pragma unroll
        for (int i = 0; i < 8; ++i) {
            v2f tt = lamp[i] + mcp[i];
            tt = __builtin_elementwise_fma(axp[i], U0, tt);
            tt = __builtin_elementwise_fma(ayp[i], U1, tt);
            tt = __builtin_elementwise_fma(azp[i], U2, tt);
            tt = __builtin_elementwise_fma(awp[i], U3, tt);
            lamp[i] = __builtin_elementwise_max(tt, z2);
        }
    }

    // ---- output: out = -(1/sc) * A'^T lam ----
    v2f a0 = (v2f){0.f, 0.f}, a1 = (v2f){0.f, 0.f};
    v2f a2 = (v2f){0.f, 0.f}, a3 = (v2f){0.f, 0.f};
#pragma unroll
    for (int i = 0; i < 8; ++i) {
        a0 = __builtin_elementwise_fma(axp[i], lamp[i], a0);
        a1 = __builtin_elementwise_fma(ayp[i], lamp[i], a1);
        a2 = __builtin_elementwise_fma(azp[i], lamp[i], a2);
        a3 = __builtin_elementwise_fma(awp[i], lamp[i], a3);
    }
    float u0 = pair_sum(a0.x + a0.y);
    float u1 = pair_sum(a1.x + a1.y);
    float u2 = pair_sum(a2.x + a2.y);
    float u3 = pair_sum(a3.x + a3.y);
    // lane j writes components 2j, 2j+1 (8B float2 store, lane-consecutive)
    float lo = (j == 0) ? u0 : u2;
    float hi = (j == 0) ? u1 : u3;
    float2 o = make_float2(-lo * inv_sc, -hi * inv_sc);
    *reinterpret_cast<float2*>(out + (size_t)p * 4 + (size_t)j * 2) = o;
}

extern "C" void kernel_launch(void* const* d_in, const int* in_sizes, int n_in,
                              void* d_out, int out_size, void* d_ws, size_t ws_size,
                              hipStream_t stream) {
    const float* A = (const float*)d_in[0];
    // d_in[1] (x) cancels analytically and is unused.
    const float* b = (const float*)d_in[2];
    float* out = (float*)d_out;

    int nprob = in_sizes[2] / 32;          // B = 32768
    int threads = nprob * 2;               // 2 lanes per problem
    dim3 block(256);
    dim3 grid((threads + 255) / 256);
    hipLaunchKernelGGL(qp_pgd_kernel, grid, block, 0, stream, A, b, out, nprob);
}